// Round 6
// baseline (96.398 us; speedup 1.0000x reference)
//
#include <hip/hip_runtime.h>

#define C 128
#define H 128
#define W 128
#define HW (H*W)

// Fused feature-propagate + 1x1 classifier (num_classes=1), one pass over feat.
// block = (b, output row r), 640 thr = 10 waves = (tap-row i in 0..4) x (ch-half h).
// lane: s = lane>>5 -> 32-channel sub-group, pg = lane&31 -> 4 px (float4).
// Per channel: 2 loads (own tap float4 + center float4); halo via __shfl_up/down.
__global__ __launch_bounds__(640, 5) void fused_kernel(
    const float* __restrict__ feat, const float* __restrict__ wc,
    const float* __restrict__ bc, float* __restrict__ out)
{
    __shared__ float corr_s[2][25][W];   // [ch-half][tap][col]
    __shared__ float g_s[2][5][W];       // [ch-half][tap-row][col]
    __shared__ float wc_s[C];

    const int blk0 = blockIdx.x;
    const int blk  = (blk0 & 7) * 64 + (blk0 >> 3);   // XCD swizzle (512 = 8*64)
    const int b    = blk >> 7;
    const int r    = blk & 127;
    const int tid  = threadIdx.x;
    const int wv   = tid >> 6;           // 0..9
    const int ti   = wv >> 1;            // tap-row index 0..4
    const int h    = wv & 1;             // 64-channel half
    const int lane = tid & 63;
    const int s    = lane >> 5;          // 32-channel sub-group
    const int pg   = lane & 31;
    const int w0   = pg * 4;             // lane owns cols w0..w0+3

    if (tid < C) wc_s[tid] = wc[tid];
    __syncthreads();

    const int  rt  = r - 4 + 2 * ti;     // wave's tap row
    const bool rok = (unsigned)rt < (unsigned)H;

    float acc[5][4];                     // corr partials, taps (ti, j) x 4 px
    float ga[4];                         // g partial for row rt
#pragma unroll
    for (int j = 0; j < 5; ++j)
#pragma unroll
        for (int p = 0; p < 4; ++p) acc[j][p] = 0.f;
#pragma unroll
    for (int p = 0; p < 4; ++p) ga[p] = 0.f;

    if (rok) {                           // wave-uniform
        const float* fbase = feat + ((size_t)(b * C + h * 64 + s * 32)) * HW;
        const float* tp = fbase + rt * W + w0;   // own tap float4
        const float* cp = fbase + r  * W + w0;   // own center float4
        const int wci = h * 64 + s * 32;
        const bool isCtr = (ti == 2);            // tap row == center row

#pragma unroll 1
        for (int cc = 0; cc < 32; cc += 4) {
            float4 T[4], D[4];
#pragma unroll
            for (int u = 0; u < 4; ++u)
                T[u] = *(const float4*)(tp + (cc + u) * HW);
            if (isCtr) {
#pragma unroll
                for (int u = 0; u < 4; ++u) D[u] = T[u];
            } else {
#pragma unroll
                for (int u = 0; u < 4; ++u)
                    D[u] = *(const float4*)(cp + (cc + u) * HW);
            }
#pragma unroll
            for (int u = 0; u < 4; ++u) {
                const float wcv = wc_s[wci + cc + u];
                const float ctr[4] = {D[u].x, D[u].y, D[u].z, D[u].w};
                // window rel cols -4..7 -> win[0..11]; tap (j,p) uses win[p+2j]
                float win[12];
                win[4] = T[u].x; win[5] = T[u].y; win[6] = T[u].z; win[7] = T[u].w;
                win[0]  = __shfl_up(T[u].x, 1);
                win[1]  = __shfl_up(T[u].y, 1);
                win[2]  = __shfl_up(T[u].z, 1);
                win[3]  = __shfl_up(T[u].w, 1);
                win[8]  = __shfl_down(T[u].x, 1);
                win[9]  = __shfl_down(T[u].y, 1);
                win[10] = __shfl_down(T[u].z, 1);
                win[11] = __shfl_down(T[u].w, 1);
                // own-col taps first (no shuffle dependency)
#pragma unroll
                for (int p = 0; p < 4; ++p)
                    ga[p] = fmaf(wcv, win[4 + p], ga[p]);
#pragma unroll
                for (int p = 0; p < 4; ++p)
                    acc[2][p] = fmaf(ctr[p], win[4 + p], acc[2][p]);
#pragma unroll
                for (int j = 0; j < 5; ++j) {
                    if (j == 2) continue;
#pragma unroll
                    for (int p = 0; p < 4; ++p)
                        acc[j][p] = fmaf(ctr[p], win[p + 2 * j], acc[j][p]);
                }
            }
        }
    }

    // reduce the two 32-channel sub-groups within the wave
#pragma unroll
    for (int j = 0; j < 5; ++j)
#pragma unroll
        for (int p = 0; p < 4; ++p)
            acc[j][p] += __shfl_xor(acc[j][p], 32);
#pragma unroll
    for (int p = 0; p < 4; ++p) ga[p] += __shfl_xor(ga[p], 32);

    // masked disjoint writes (s==0 lanes cover all 128 cols)
    if (s == 0) {
#pragma unroll
        for (int j = 0; j < 5; ++j)
#pragma unroll
            for (int p = 0; p < 4; ++p) {
                const int  col = w0 + p - 4 + 2 * j;
                const bool ok  = rok && ((unsigned)col < (unsigned)W);
                corr_s[h][ti * 5 + j][w0 + p] = ok ? acc[j][p] : 0.f;
            }
#pragma unroll
        for (int p = 0; p < 4; ++p) g_s[h][ti][w0 + p] = ga[p];  // 0 if !rok
    }
    __syncthreads();

    // relu -> softmax over 25 taps -> sum attn * g -> + bias
    if (tid < W) {
        const int w = tid;
        float v[25], m = 0.f;
#pragma unroll
        for (int n = 0; n < 25; ++n) {
            v[n] = fmaxf(corr_s[0][n][w] + corr_s[1][n][w], 0.f);
            m = fmaxf(m, v[n]);
        }
        float sum = 0.f, num = 0.f;
#pragma unroll
        for (int i = 0; i < 5; ++i) {
            const bool riv = (unsigned)(r - 4 + 2 * i) < (unsigned)H;
#pragma unroll
            for (int j = 0; j < 5; ++j) {
                const float e = __expf(v[i * 5 + j] - m);
                sum += e;
                const int  wt = w - 4 + 2 * j;
                const bool ok = riv && ((unsigned)wt < (unsigned)W);
                const int  wi = ok ? wt : 0;
                const float gv = g_s[0][i][wi] + g_s[1][i][wi];
                num = fmaf(e, ok ? gv : 0.f, num);
            }
        }
        out[((size_t)(b * H + r)) * W + w] = num / sum + bc[0];
    }
}

extern "C" void kernel_launch(void* const* d_in, const int* in_sizes, int n_in,
                              void* d_out, int out_size, void* d_ws, size_t ws_size,
                              hipStream_t stream) {
    const float* feat = (const float*)d_in[0];
    const float* wcls = (const float*)d_in[1];
    const float* bcls = (const float*)d_in[2];
    float* outp = (float*)d_out;

    fused_kernel<<<dim3(4 * H), dim3(640), 0, stream>>>(feat, wcls, bcls, outp);
}